// Round 1
// baseline (130.370 us; speedup 1.0000x reference)
//
#include <hip/hip_runtime.h>

#define NB 8
#define TNEW 128
#define CMAX 2048
#define DMODEL 1024
#define NH 16
#define DH 64

typedef float f32x4 __attribute__((ext_vector_type(4)));
typedef short short8 __attribute__((ext_vector_type(8)));
typedef short short4v __attribute__((ext_vector_type(4)));

__device__ __forceinline__ short f2bf(float x) {
  unsigned u = __float_as_uint(x);
  u += 0x7FFFu + ((u >> 16) & 1u);   // RTNE
  return (short)(u >> 16);
}
__device__ __forceinline__ float bf2f(short s) {
  return __uint_as_float(((unsigned)(unsigned short)s) << 16);
}
__device__ __forceinline__ short8 cvt8(f32x4 a, f32x4 b) {
  short8 o;
  o[0] = f2bf(a.x); o[1] = f2bf(a.y); o[2] = f2bf(a.z); o[3] = f2bf(a.w);
  o[4] = f2bf(b.x); o[5] = f2bf(b.y); o[6] = f2bf(b.z); o[7] = f2bf(b.w);
  return o;
}

// ---------------- f32 -> bf16 convert ----------------
__global__ __launch_bounds__(256) void cvt_bf16(const float* __restrict__ src,
                                                short* __restrict__ dst, int n4) {
  int i = blockIdx.x * 256 + threadIdx.x;
  if (i >= n4) return;
  f32x4 v = *(const f32x4*)(src + (size_t)i * 4);
  short4v o;
  o.x = f2bf(v.x); o.y = f2bf(v.y); o.z = f2bf(v.z); o.w = f2bf(v.w);
  *(short4v*)(dst + (size_t)i * 4) = o;
}

// ---------------- GEMM: C[r,n] = sum_m A[r,m] * W[n,m] (+bias) ----------------
// A: M x 1024 bf16 row-major. W: 1024 x 1024 bf16 row-major (N x K).
// MODE 0: out bf16 to ws (z in {0,1,2} selects Wq/Wk/Wv and q/k/v dest)
// MODE 1: out f32 to d_out with valid-row masking.
template<int MODE>
__global__ __launch_bounds__(256) void gemm64(
    const short* __restrict__ A, const short* __restrict__ Wbase,
    void* __restrict__ Out, const float* __restrict__ bias0,
    const float* __restrict__ bias1, const float* __restrict__ bias2,
    const int* __restrict__ new_len)
{
  constexpr int LDT = 40;  // padded LDS stride (shorts): 80 B, 16B-aligned, bank-uniform
  __shared__ short As[64 * LDT];
  __shared__ short Bs[64 * LDT];
  const int n0 = blockIdx.x * 64, m0 = blockIdx.y * 64, z = blockIdx.z;
  const short* Wp = Wbase + (size_t)z * (DMODEL * DMODEL);
  const float* bias = (MODE == 0) ? (z == 0 ? bias0 : (z == 1 ? bias1 : bias2)) : bias0;
  const int tid = threadIdx.x, lane = tid & 63, w = tid >> 6;
  const int wm = (w >> 1) * 32, wn = (w & 1) * 32;
  const int lr = lane & 15, lk = lane >> 4;

  const int srow = tid >> 2, soff = (tid & 3) * 8;
  const short* Ag = A  + (size_t)(m0 + srow) * DMODEL + soff;
  const short* Bg = Wp + (size_t)(n0 + srow) * DMODEL + soff;
  short* Al = As + srow * LDT + soff;
  short* Bl = Bs + srow * LDT + soff;

  f32x4 acc[2][2] = {};
  for (int kt = 0; kt < DMODEL / 32; ++kt) {
    short8 va = *(const short8*)(Ag + kt * 32);
    short8 vb = *(const short8*)(Bg + kt * 32);
    __syncthreads();
    *(short8*)Al = va;
    *(short8*)Bl = vb;
    __syncthreads();
    short8 af[2], bfr[2];
    af[0]  = *(const short8*)(As + (wm + lr) * LDT + lk * 8);
    af[1]  = *(const short8*)(As + (wm + 16 + lr) * LDT + lk * 8);
    bfr[0] = *(const short8*)(Bs + (wn + lr) * LDT + lk * 8);
    bfr[1] = *(const short8*)(Bs + (wn + 16 + lr) * LDT + lk * 8);
#pragma unroll
    for (int i = 0; i < 2; ++i)
#pragma unroll
      for (int j = 0; j < 2; ++j)
        acc[i][j] = __builtin_amdgcn_mfma_f32_16x16x32_bf16(af[i], bfr[j], acc[i][j], 0, 0, 0);
  }
#pragma unroll
  for (int i = 0; i < 2; ++i) {
#pragma unroll
    for (int j = 0; j < 2; ++j) {
      const int col = n0 + wn + j * 16 + lr;
      const float bcol = bias[col];
#pragma unroll
      for (int r = 0; r < 4; ++r) {
        const int row = m0 + wm + i * 16 + lk * 4 + r;  // C/D: row=(lane>>4)*4+reg, col=lane&15
        float v = acc[i][j][r] + bcol;
        if (MODE == 0) {
          ((short*)Out)[(size_t)z * (NB * TNEW * DMODEL) + (size_t)row * DMODEL + col] = f2bf(v);
        } else {
          const int bb = row >> 7, t = row & 127;
          ((float*)Out)[(size_t)row * DMODEL + col] = (t < new_len[bb]) ? v : 0.0f;
        }
      }
    }
  }
}

// ---------------- RoPE + validity masking on q,k (and v mask) ----------------
__global__ __launch_bounds__(256) void rope_mask(
    short* __restrict__ qb, short* __restrict__ kb, short* __restrict__ vb,
    const float* __restrict__ inv_freq, const int* __restrict__ past_len,
    const int* __restrict__ new_len)
{
  const int idx = blockIdx.x * 256 + threadIdx.x;  // B*T*H*32 = 524288
  const int d = idx & 31;
  const int h = (idx >> 5) & 15;
  const int t = (idx >> 9) & 127;
  const int b = idx >> 16;
  const bool valid = t < new_len[b];
  const float pos = (float)(past_len[b] + t);
  float sn, cs;
  sincosf(pos * inv_freq[d], &sn, &cs);
  const size_t base = (size_t)(b * 128 + t) * DMODEL + h * 64 + d;
  const float q1 = bf2f(qb[base]), q2 = bf2f(qb[base + 32]);
  const float k1 = bf2f(kb[base]), k2 = bf2f(kb[base + 32]);
  qb[base]      = valid ? f2bf(q1 * cs - q2 * sn) : (short)0;
  qb[base + 32] = valid ? f2bf(q2 * cs + q1 * sn) : (short)0;
  kb[base]      = valid ? f2bf(k1 * cs - k2 * sn) : (short)0;
  kb[base + 32] = valid ? f2bf(k2 * cs + k1 * sn) : (short)0;
  if (!valid) { vb[base] = 0; vb[base + 32] = 0; }
}

// ---------------- flash attention over past+new keys ----------------
// 1 block per (b,h), 512 threads = 8 waves, wave w owns q rows [w*16, w*16+16)
__global__ __launch_bounds__(512) void attn_fwd(
    const float* __restrict__ pk, const float* __restrict__ pv,
    const short* __restrict__ qb, const short* __restrict__ kb,
    const short* __restrict__ vb, short* __restrict__ ctxb,
    const int* __restrict__ past_len, const int* __restrict__ new_len)
{
  constexpr int LDT = 72;  // padded stride: 144 B, 16B-aligned, bank-uniform
  __shared__ short Kl[64 * LDT];    // [key][d]
  __shared__ short Vt[64 * LDT];    // [d][key] (transposed)
  __shared__ short Pl[128 * LDT];   // [q][key], per-wave private rows
  const int bh = blockIdx.x, b = bh >> 4, h = bh & 15;
  const int past = past_len[b];
  const int total = past + new_len[b];
  const int tid = threadIdx.x, lane = tid & 63, w = tid >> 6;
  const int lr = lane & 15, lk = lane >> 4;

  // Q fragments: A-layout row = lane%16, k = 8*(lane/16)+j
  short8 qf0, qf1;
  {
    const short* qrow = qb + (size_t)(b * 128 + w * 16 + lr) * DMODEL + h * 64;
    qf0 = *(const short8*)(qrow + lk * 8);
    qf1 = *(const short8*)(qrow + 32 + lk * 8);
  }
  float m_run[4], l_run[4];
  f32x4 acc[4] = {};
#pragma unroll
  for (int r = 0; r < 4; ++r) { m_run[r] = -3.0e38f; l_run[r] = 0.f; }

  const int jr = tid >> 3, seg = tid & 7;   // staging: row jr, 8 d's per thread
  const int nt = (total + 63) >> 6;
  for (int kt = 0; kt < nt; ++kt) {
    {  // ---- stage K tile + V tile (transposed) ----
      const int j = kt * 64 + jr;
      short8 kr = {}, vr = {};
      if (j < past) {
        const float* kp = pk + ((size_t)(b * 16 + h) * CMAX + j) * 64 + seg * 8;
        const float* vp = pv + ((size_t)(b * 16 + h) * CMAX + j) * 64 + seg * 8;
        kr = cvt8(*(const f32x4*)kp, *(const f32x4*)(kp + 4));
        vr = cvt8(*(const f32x4*)vp, *(const f32x4*)(vp + 4));
      } else if (j < total) {
        const short* kp = kb + (size_t)(b * 128 + (j - past)) * DMODEL + h * 64 + seg * 8;
        const short* vp = vb + (size_t)(b * 128 + (j - past)) * DMODEL + h * 64 + seg * 8;
        kr = *(const short8*)kp;
        vr = *(const short8*)vp;
      }
      *(short8*)(Kl + jr * LDT + seg * 8) = kr;
#pragma unroll
      for (int i = 0; i < 8; ++i) Vt[(seg * 8 + i) * LDT + jr] = vr[i];
    }
    __syncthreads();

    // ---- S = Q K^T (per wave: 16 q x 64 keys) ----
    f32x4 s[4];
#pragma unroll
    for (int nf = 0; nf < 4; ++nf) {
      short8 k0 = *(const short8*)(Kl + (nf * 16 + lr) * LDT + lk * 8);
      short8 k1 = *(const short8*)(Kl + (nf * 16 + lr) * LDT + 32 + lk * 8);
      f32x4 zv = {};
      zv = __builtin_amdgcn_mfma_f32_16x16x32_bf16(qf0, k0, zv, 0, 0, 0);
      s[nf] = __builtin_amdgcn_mfma_f32_16x16x32_bf16(qf1, k1, zv, 0, 0, 0);
    }
    // ---- scale + mask + online softmax ----
    const int kg0 = kt * 64;
    float pmax[4] = {-3.0e38f, -3.0e38f, -3.0e38f, -3.0e38f};
#pragma unroll
    for (int nf = 0; nf < 4; ++nf) {
      const bool ok = (kg0 + nf * 16 + lr) < total;
#pragma unroll
      for (int r = 0; r < 4; ++r) {
        const float sv = ok ? s[nf][r] * 0.125f : -3.0e38f;
        s[nf][r] = sv;
        pmax[r] = fmaxf(pmax[r], sv);
      }
    }
#pragma unroll
    for (int r = 0; r < 4; ++r) {
#pragma unroll
      for (int off = 1; off < 16; off <<= 1)
        pmax[r] = fmaxf(pmax[r], __shfl_xor(pmax[r], off));
    }
    float alpha[4], rsum[4];
#pragma unroll
    for (int r = 0; r < 4; ++r) {
      const float mn = fmaxf(m_run[r], pmax[r]);
      alpha[r] = __expf(m_run[r] - mn);
      m_run[r] = mn;
      rsum[r] = 0.f;
    }
#pragma unroll
    for (int nf = 0; nf < 4; ++nf)
#pragma unroll
      for (int r = 0; r < 4; ++r) {
        const float p = __expf(s[nf][r] - m_run[r]);
        s[nf][r] = p;
        rsum[r] += p;
      }
#pragma unroll
    for (int r = 0; r < 4; ++r) {
#pragma unroll
      for (int off = 1; off < 16; off <<= 1)
        rsum[r] += __shfl_xor(rsum[r], off);
      l_run[r] = l_run[r] * alpha[r] + rsum[r];
    }
#pragma unroll
    for (int nf = 0; nf < 4; ++nf)
#pragma unroll
      for (int r = 0; r < 4; ++r) acc[nf][r] *= alpha[r];

    // ---- P -> LDS (C-layout rows), then PV MFMAs (same-wave RAW: in-order DS) ----
#pragma unroll
    for (int nf = 0; nf < 4; ++nf)
#pragma unroll
      for (int r = 0; r < 4; ++r)
        Pl[(w * 16 + lk * 4 + r) * LDT + nf * 16 + lr] = f2bf(s[nf][r]);
#pragma unroll
    for (int kf = 0; kf < 2; ++kf) {
      short8 pf = *(const short8*)(Pl + (w * 16 + lr) * LDT + kf * 32 + lk * 8);
#pragma unroll
      for (int nf = 0; nf < 4; ++nf) {
        short8 vf = *(const short8*)(Vt + (nf * 16 + lr) * LDT + kf * 32 + lk * 8);
        acc[nf] = __builtin_amdgcn_mfma_f32_16x16x32_bf16(pf, vf, acc[nf], 0, 0, 0);
      }
    }
    __syncthreads();  // protect Kl/Vt before next stage
  }
  // ---- epilogue: ctx = O / l, bf16 into ws ----
#pragma unroll
  for (int nf = 0; nf < 4; ++nf)
#pragma unroll
    for (int r = 0; r < 4; ++r) {
      const int q = w * 16 + lk * 4 + r, d = nf * 16 + lr;
      ctxb[(size_t)(b * 128 + q) * DMODEL + h * 64 + d] = f2bf(acc[nf][r] / l_run[r]);
    }
}

// ---------------- launcher ----------------
extern "C" void kernel_launch(void* const* d_in, const int* in_sizes, int n_in,
                              void* d_out, int out_size, void* d_ws, size_t ws_size,
                              hipStream_t stream) {
  const float* x      = (const float*)d_in[0];
  const float* past_k = (const float*)d_in[1];
  const float* past_v = (const float*)d_in[2];
  const float* Wq = (const float*)d_in[3];
  const float* bq = (const float*)d_in[4];
  const float* Wk = (const float*)d_in[5];
  const float* bk = (const float*)d_in[6];
  const float* Wv = (const float*)d_in[7];
  const float* bv = (const float*)d_in[8];
  const float* Wo = (const float*)d_in[9];
  const float* bo = (const float*)d_in[10];
  const float* inv_freq = (const float*)d_in[11];
  const int* past_len = (const int*)d_in[12];
  const int* new_len  = (const int*)d_in[13];

  // ws layout (shorts): Xb | Wq | Wk | Wv | Wo | q | k | v | ctx  = 9 MiShorts = 18 MB
  short* wsb = (short*)d_ws;
  const size_t M1 = 1u << 20;
  short* Xb  = wsb;
  short* Wqb = wsb + 1 * M1;
  short* Wob = wsb + 4 * M1;
  short* qb  = wsb + 5 * M1;
  short* kb  = wsb + 6 * M1;
  short* vb  = wsb + 7 * M1;
  short* ctx = wsb + 8 * M1;

  cvt_bf16<<<1024, 256, 0, stream>>>(x,  Xb,          262144);
  cvt_bf16<<<1024, 256, 0, stream>>>(Wq, Wqb,         262144);
  cvt_bf16<<<1024, 256, 0, stream>>>(Wk, wsb + 2 * M1, 262144);
  cvt_bf16<<<1024, 256, 0, stream>>>(Wv, wsb + 3 * M1, 262144);
  cvt_bf16<<<1024, 256, 0, stream>>>(Wo, Wob,         262144);

  gemm64<0><<<dim3(16, 16, 3), 256, 0, stream>>>(Xb, Wqb, (void*)qb, bq, bk, bv, nullptr);
  rope_mask<<<2048, 256, 0, stream>>>(qb, kb, vb, inv_freq, past_len, new_len);
  attn_fwd<<<128, 512, 0, stream>>>(past_k, past_v, qb, kb, vb, ctx, past_len, new_len);
  gemm64<1><<<dim3(16, 16, 1), 256, 0, stream>>>(ctx, Wob, d_out, bo, nullptr, nullptr, new_len);
}

// Round 2
// 85.710 us; speedup vs baseline: 1.5211x; 1.5211x over previous
//
#include <hip/hip_runtime.h>

#define NB 8
#define TNEW 128
#define CMAX 2048
#define DMODEL 1024
#define NH 16
#define DH 64

typedef float f32x4 __attribute__((ext_vector_type(4)));
typedef short short8 __attribute__((ext_vector_type(8)));
typedef short short4v __attribute__((ext_vector_type(4)));

__device__ __forceinline__ short f2bf(float x) {
  unsigned u = __float_as_uint(x);
  u += 0x7FFFu + ((u >> 16) & 1u);   // RTNE
  return (short)(u >> 16);
}
__device__ __forceinline__ float bf2f(short s) {
  return __uint_as_float(((unsigned)(unsigned short)s) << 16);
}
__device__ __forceinline__ short8 cvt8(f32x4 a, f32x4 b) {
  short8 o;
  o[0] = f2bf(a.x); o[1] = f2bf(a.y); o[2] = f2bf(a.z); o[3] = f2bf(a.w);
  o[4] = f2bf(b.x); o[5] = f2bf(b.y); o[6] = f2bf(b.z); o[7] = f2bf(b.w);
  return o;
}

// ---------------- fused f32 -> bf16 convert: x, Wq, Wk, Wv, Wo ----------------
// 5 segments x 262144 f32x4 each; dst segment stride = 1 Mi shorts.
__global__ __launch_bounds__(256) void cvt5_bf16(
    const float* __restrict__ s0, const float* __restrict__ s1,
    const float* __restrict__ s2, const float* __restrict__ s3,
    const float* __restrict__ s4, short* __restrict__ dst) {
  const int seg = blockIdx.x >> 10;
  const int i = (blockIdx.x & 1023) * 256 + threadIdx.x;
  const float* src = seg == 0 ? s0 : seg == 1 ? s1 : seg == 2 ? s2 : seg == 3 ? s3 : s4;
  f32x4 v = *(const f32x4*)(src + (size_t)i * 4);
  short4v o;
  o.x = f2bf(v.x); o.y = f2bf(v.y); o.z = f2bf(v.z); o.w = f2bf(v.w);
  *(short4v*)(dst + (size_t)seg * (1u << 20) + (size_t)i * 4) = o;
}

// ---------------- GEMM: C[r,n] = sum_m A[r,m] * W[n,m] (+bias) ----------------
template<int MODE>
__global__ __launch_bounds__(256) void gemm64(
    const short* __restrict__ A, const short* __restrict__ Wbase,
    void* __restrict__ Out, const float* __restrict__ bias0,
    const float* __restrict__ bias1, const float* __restrict__ bias2,
    const int* __restrict__ new_len)
{
  constexpr int LDT = 40;  // padded LDS stride (shorts): 80 B, 16B-aligned, bank-uniform
  __shared__ short As[64 * LDT];
  __shared__ short Bs[64 * LDT];
  const int n0 = blockIdx.x * 64, m0 = blockIdx.y * 64, z = blockIdx.z;
  const short* Wp = Wbase + (size_t)z * (DMODEL * DMODEL);
  const float* bias = (MODE == 0) ? (z == 0 ? bias0 : (z == 1 ? bias1 : bias2)) : bias0;
  const int tid = threadIdx.x, lane = tid & 63, w = tid >> 6;
  const int wm = (w >> 1) * 32, wn = (w & 1) * 32;
  const int lr = lane & 15, lk = lane >> 4;

  const int srow = tid >> 2, soff = (tid & 3) * 8;
  const short* Ag = A  + (size_t)(m0 + srow) * DMODEL + soff;
  const short* Bg = Wp + (size_t)(n0 + srow) * DMODEL + soff;
  short* Al = As + srow * LDT + soff;
  short* Bl = Bs + srow * LDT + soff;

  f32x4 acc[2][2] = {};
  for (int kt = 0; kt < DMODEL / 32; ++kt) {
    short8 va = *(const short8*)(Ag + kt * 32);
    short8 vb = *(const short8*)(Bg + kt * 32);
    __syncthreads();
    *(short8*)Al = va;
    *(short8*)Bl = vb;
    __syncthreads();
    short8 af[2], bfr[2];
    af[0]  = *(const short8*)(As + (wm + lr) * LDT + lk * 8);
    af[1]  = *(const short8*)(As + (wm + 16 + lr) * LDT + lk * 8);
    bfr[0] = *(const short8*)(Bs + (wn + lr) * LDT + lk * 8);
    bfr[1] = *(const short8*)(Bs + (wn + 16 + lr) * LDT + lk * 8);
#pragma unroll
    for (int i = 0; i < 2; ++i)
#pragma unroll
      for (int j = 0; j < 2; ++j)
        acc[i][j] = __builtin_amdgcn_mfma_f32_16x16x32_bf16(af[i], bfr[j], acc[i][j], 0, 0, 0);
  }
#pragma unroll
  for (int i = 0; i < 2; ++i) {
#pragma unroll
    for (int j = 0; j < 2; ++j) {
      const int col = n0 + wn + j * 16 + lr;
      const float bcol = bias[col];
#pragma unroll
      for (int r = 0; r < 4; ++r) {
        const int row = m0 + wm + i * 16 + lk * 4 + r;
        float v = acc[i][j][r] + bcol;
        if (MODE == 0) {
          ((short*)Out)[(size_t)z * (NB * TNEW * DMODEL) + (size_t)row * DMODEL + col] = f2bf(v);
        } else {
          const int bb = row >> 7, t = row & 127;
          ((float*)Out)[(size_t)row * DMODEL + col] = (t < new_len[bb]) ? v : 0.0f;
        }
      }
    }
  }
}

// ---------------- RoPE + validity masking on q,k (and v mask) ----------------
__global__ __launch_bounds__(256) void rope_mask(
    short* __restrict__ qb, short* __restrict__ kb, short* __restrict__ vb,
    const float* __restrict__ inv_freq, const int* __restrict__ past_len,
    const int* __restrict__ new_len)
{
  const int idx = blockIdx.x * 256 + threadIdx.x;  // B*T*H*32 = 524288
  const int d = idx & 31;
  const int h = (idx >> 5) & 15;
  const int t = (idx >> 9) & 127;
  const int b = idx >> 16;
  const bool valid = t < new_len[b];
  const float pos = (float)(past_len[b] + t);
  float sn, cs;
  sincosf(pos * inv_freq[d], &sn, &cs);
  const size_t base = (size_t)(b * 128 + t) * DMODEL + h * 64 + d;
  const float q1 = bf2f(qb[base]), q2 = bf2f(qb[base + 32]);
  const float k1 = bf2f(kb[base]), k2 = bf2f(kb[base + 32]);
  qb[base]      = valid ? f2bf(q1 * cs - q2 * sn) : (short)0;
  qb[base + 32] = valid ? f2bf(q2 * cs + q1 * sn) : (short)0;
  kb[base]      = valid ? f2bf(k1 * cs - k2 * sn) : (short)0;
  kb[base + 32] = valid ? f2bf(k2 * cs + k1 * sn) : (short)0;
  if (!valid) { vb[base] = 0; vb[base + 32] = 0; }
}

// ---------------- split-K flash attention: partial (O, m, l) per split ----------------
// grid: (bh=128, split). 512 threads = 8 waves, wave w owns q rows [w*16, w*16+16)
__global__ __launch_bounds__(512) void attn_split(
    const float* __restrict__ pk, const float* __restrict__ pv,
    const short* __restrict__ qb, const short* __restrict__ kb,
    const short* __restrict__ vb, float* __restrict__ Opart,
    float* __restrict__ Ml, const int* __restrict__ past_len,
    const int* __restrict__ new_len, int splits)
{
  constexpr int LDT = 72;  // padded stride: 144 B, 16B-aligned, bank-uniform
  __shared__ short Kl[64 * LDT];    // [key][d]
  __shared__ short Vt[64 * LDT];    // [d][key] (transposed)
  __shared__ short Pl[128 * LDT];   // [q][key], per-wave private rows
  const int bh = blockIdx.x, b = bh >> 4, h = bh & 15;
  const int s = blockIdx.y;
  const int past = past_len[b];
  const int total = past + new_len[b];
  const int tid = threadIdx.x, lane = tid & 63, w = tid >> 6;
  const int lr = lane & 15, lk = lane >> 4;

  const int nt = (total + 63) >> 6;
  const int ntp = (nt + splits - 1) / splits;
  const int t0 = s * ntp;
  const int t1 = min(nt, t0 + ntp);

  float* mlp = Ml + (size_t)(bh * splits + s) * 256;
  float* op  = Opart + (size_t)(bh * splits + s) * (128 * 64);

  if (t0 >= t1) {  // empty split: weight 0 in combine (O left as-is, w=0 nullifies)
#pragma unroll
    for (int r = 0; r < 4; ++r) {
      const int q = w * 16 + lk * 4 + r;
      if (lr == 0) { mlp[q] = -3.0e38f; mlp[128 + q] = 0.f; }
    }
    // still must zero O: combine multiplies by exp(-3e38 - m*) == 0, but keep it
    // finite: ws may hold 0xAA pattern (finite float), 0 * finite == 0. Safe to skip.
    return;
  }

  short8 qf0, qf1;
  {
    const short* qrow = qb + (size_t)(b * 128 + w * 16 + lr) * DMODEL + h * 64;
    qf0 = *(const short8*)(qrow + lk * 8);
    qf1 = *(const short8*)(qrow + 32 + lk * 8);
  }
  float m_run[4], l_run[4];
  f32x4 acc[4] = {};
#pragma unroll
  for (int r = 0; r < 4; ++r) { m_run[r] = -3.0e38f; l_run[r] = 0.f; }

  const int jr = tid >> 3, seg = tid & 7;   // staging: row jr, 8 d's per thread
  for (int kt = t0; kt < t1; ++kt) {
    {  // ---- stage K tile + V tile (transposed) ----
      const int j = kt * 64 + jr;
      short8 kr = {}, vr = {};
      if (j < past) {
        const float* kp = pk + ((size_t)(b * 16 + h) * CMAX + j) * 64 + seg * 8;
        const float* vp = pv + ((size_t)(b * 16 + h) * CMAX + j) * 64 + seg * 8;
        kr = cvt8(*(const f32x4*)kp, *(const f32x4*)(kp + 4));
        vr = cvt8(*(const f32x4*)vp, *(const f32x4*)(vp + 4));
      } else if (j < total) {
        const short* kp = kb + (size_t)(b * 128 + (j - past)) * DMODEL + h * 64 + seg * 8;
        const short* vp = vb + (size_t)(b * 128 + (j - past)) * DMODEL + h * 64 + seg * 8;
        kr = *(const short8*)kp;
        vr = *(const short8*)vp;
      }
      *(short8*)(Kl + jr * LDT + seg * 8) = kr;
#pragma unroll
      for (int i = 0; i < 8; ++i) Vt[(seg * 8 + i) * LDT + jr] = vr[i];
    }
    __syncthreads();

    // ---- S = Q K^T (per wave: 16 q x 64 keys) ----
    f32x4 sc[4];
#pragma unroll
    for (int nf = 0; nf < 4; ++nf) {
      short8 k0 = *(const short8*)(Kl + (nf * 16 + lr) * LDT + lk * 8);
      short8 k1 = *(const short8*)(Kl + (nf * 16 + lr) * LDT + 32 + lk * 8);
      f32x4 zv = {};
      zv = __builtin_amdgcn_mfma_f32_16x16x32_bf16(qf0, k0, zv, 0, 0, 0);
      sc[nf] = __builtin_amdgcn_mfma_f32_16x16x32_bf16(qf1, k1, zv, 0, 0, 0);
    }
    // ---- scale + mask + online softmax ----
    const int kg0 = kt * 64;
    float pmax[4] = {-3.0e38f, -3.0e38f, -3.0e38f, -3.0e38f};
#pragma unroll
    for (int nf = 0; nf < 4; ++nf) {
      const bool ok = (kg0 + nf * 16 + lr) < total;
#pragma unroll
      for (int r = 0; r < 4; ++r) {
        const float sv = ok ? sc[nf][r] * 0.125f : -3.0e38f;
        sc[nf][r] = sv;
        pmax[r] = fmaxf(pmax[r], sv);
      }
    }
#pragma unroll
    for (int r = 0; r < 4; ++r) {
#pragma unroll
      for (int off = 1; off < 16; off <<= 1)
        pmax[r] = fmaxf(pmax[r], __shfl_xor(pmax[r], off));
    }
    float alpha[4], rsum[4];
#pragma unroll
    for (int r = 0; r < 4; ++r) {
      const float mn = fmaxf(m_run[r], pmax[r]);
      alpha[r] = __expf(m_run[r] - mn);
      m_run[r] = mn;
      rsum[r] = 0.f;
    }
#pragma unroll
    for (int nf = 0; nf < 4; ++nf)
#pragma unroll
      for (int r = 0; r < 4; ++r) {
        const float p = __expf(sc[nf][r] - m_run[r]);
        sc[nf][r] = p;
        rsum[r] += p;
      }
#pragma unroll
    for (int r = 0; r < 4; ++r) {
#pragma unroll
      for (int off = 1; off < 16; off <<= 1)
        rsum[r] += __shfl_xor(rsum[r], off);
      l_run[r] = l_run[r] * alpha[r] + rsum[r];
    }
#pragma unroll
    for (int nf = 0; nf < 4; ++nf)
#pragma unroll
      for (int r = 0; r < 4; ++r) acc[nf][r] *= alpha[r];

    // ---- P -> LDS (C-layout rows), then PV MFMAs (same-wave RAW: in-order DS) ----
#pragma unroll
    for (int nf = 0; nf < 4; ++nf)
#pragma unroll
      for (int r = 0; r < 4; ++r)
        Pl[(w * 16 + lk * 4 + r) * LDT + nf * 16 + lr] = f2bf(sc[nf][r]);
#pragma unroll
    for (int kf = 0; kf < 2; ++kf) {
      short8 pf = *(const short8*)(Pl + (w * 16 + lr) * LDT + kf * 32 + lk * 8);
#pragma unroll
      for (int nf = 0; nf < 4; ++nf) {
        short8 vf = *(const short8*)(Vt + (nf * 16 + lr) * LDT + kf * 32 + lk * 8);
        acc[nf] = __builtin_amdgcn_mfma_f32_16x16x32_bf16(pf, vf, acc[nf], 0, 0, 0);
      }
    }
    __syncthreads();  // protect Kl/Vt before next stage
  }
  // ---- epilogue: partial O (unnormalized), m, l ----
#pragma unroll
  for (int nf = 0; nf < 4; ++nf)
#pragma unroll
    for (int r = 0; r < 4; ++r) {
      const int q = w * 16 + lk * 4 + r, d = nf * 16 + lr;
      op[(size_t)q * 64 + d] = acc[nf][r];
    }
#pragma unroll
  for (int r = 0; r < 4; ++r) {
    const int q = w * 16 + lk * 4 + r;
    if (lr == 0) { mlp[q] = m_run[r]; mlp[128 + q] = l_run[r]; }
  }
}

// ---------------- combine partials -> ctx (bf16) ----------------
// grid (bh=128, qgroup=8), 256 threads: q = qg*16 + t>>4, d = (t&15)*4
__global__ __launch_bounds__(256) void attn_combine(
    const float* __restrict__ Opart, const float* __restrict__ Ml,
    short* __restrict__ ctxb, int splits)
{
  const int bh = blockIdx.x, b = bh >> 4, h = bh & 15;
  const int q = blockIdx.y * 16 + (threadIdx.x >> 4);
  const int dv = (threadIdx.x & 15) * 4;
  const float* mlb = Ml + (size_t)bh * splits * 256;
  float mstar = -3.0e38f;
  for (int s = 0; s < splits; ++s)
    mstar = fmaxf(mstar, mlb[s * 256 + q]);
  float lsum = 0.f;
  f32x4 o = {};
  for (int s = 0; s < splits; ++s) {
    const float ws = __expf(mlb[s * 256 + q] - mstar);
    lsum += ws * mlb[s * 256 + 128 + q];
    f32x4 ov = *(const f32x4*)(Opart + ((size_t)(bh * splits + s) * 128 + q) * 64 + dv);
    o.x += ws * ov.x; o.y += ws * ov.y; o.z += ws * ov.z; o.w += ws * ov.w;
  }
  const float inv = 1.0f / lsum;
  short4v r;
  r.x = f2bf(o.x * inv); r.y = f2bf(o.y * inv); r.z = f2bf(o.z * inv); r.w = f2bf(o.w * inv);
  *(short4v*)(ctxb + (size_t)(b * 128 + q) * DMODEL + h * 64 + dv) = r;
}

// ---------------- launcher ----------------
extern "C" void kernel_launch(void* const* d_in, const int* in_sizes, int n_in,
                              void* d_out, int out_size, void* d_ws, size_t ws_size,
                              hipStream_t stream) {
  const float* x      = (const float*)d_in[0];
  const float* past_k = (const float*)d_in[1];
  const float* past_v = (const float*)d_in[2];
  const float* Wq = (const float*)d_in[3];
  const float* bq = (const float*)d_in[4];
  const float* Wk = (const float*)d_in[5];
  const float* bk = (const float*)d_in[6];
  const float* Wv = (const float*)d_in[7];
  const float* bv = (const float*)d_in[8];
  const float* Wo = (const float*)d_in[9];
  const float* bo = (const float*)d_in[10];
  const float* inv_freq = (const float*)d_in[11];
  const int* past_len = (const int*)d_in[12];
  const int* new_len  = (const int*)d_in[13];

  // ws layout (shorts): Xb | Wq | Wk | Wv | Wo | q | k | v | ctx = 9 Mi shorts (18 MB)
  // then f32: Opart[128*splits*128*64] | Ml[128*splits*256]
  short* wsb = (short*)d_ws;
  const size_t M1 = 1u << 20;
  short* Xb  = wsb;
  short* Wqb = wsb + 1 * M1;
  short* Wob = wsb + 4 * M1;
  short* qb  = wsb + 5 * M1;
  short* kb  = wsb + 6 * M1;
  short* vb  = wsb + 7 * M1;
  short* ctx = wsb + 8 * M1;
  float* Opart = (float*)(wsb + 9 * M1);

  int splits = 1;
  for (int s = 8; s >= 1; s >>= 1) {
    size_t need = 9 * M1 * sizeof(short) +
                  (size_t)s * 128 * (128 * 64 + 256) * sizeof(float);
    if (need <= ws_size) { splits = s; break; }
  }
  float* Ml = Opart + (size_t)128 * splits * (128 * 64);

  cvt5_bf16<<<5120, 256, 0, stream>>>(x, Wq, Wk, Wv, Wo, wsb);

  gemm64<0><<<dim3(16, 16, 3), 256, 0, stream>>>(Xb, Wqb, (void*)qb, bq, bk, bv, nullptr);
  rope_mask<<<2048, 256, 0, stream>>>(qb, kb, vb, inv_freq, past_len, new_len);
  attn_split<<<dim3(128, splits), 512, 0, stream>>>(past_k, past_v, qb, kb, vb,
                                                    Opart, Ml, past_len, new_len, splits);
  attn_combine<<<dim3(128, 8), 256, 0, stream>>>(Opart, Ml, ctx, splits);
  gemm64<1><<<dim3(16, 16, 1), 256, 0, stream>>>(ctx, Wob, d_out, bo, nullptr, nullptr, new_len);
}

// Round 3
// 76.338 us; speedup vs baseline: 1.7078x; 1.1228x over previous
//
#include <hip/hip_runtime.h>

#define NB 8
#define TNEW 128
#define CMAX 2048
#define DMODEL 1024
#define NH 16
#define DH 64

typedef float f32x4 __attribute__((ext_vector_type(4)));
typedef short short8 __attribute__((ext_vector_type(8)));
typedef short short4v __attribute__((ext_vector_type(4)));

__device__ __forceinline__ short f2bf(float x) {
  unsigned u = __float_as_uint(x);
  u += 0x7FFFu + ((u >> 16) & 1u);   // RTNE
  return (short)(u >> 16);
}
__device__ __forceinline__ float bf2f(short s) {
  return __uint_as_float(((unsigned)(unsigned short)s) << 16);
}
__device__ __forceinline__ short8 cvt8(f32x4 a, f32x4 b) {
  short8 o;
  o[0] = f2bf(a.x); o[1] = f2bf(a.y); o[2] = f2bf(a.z); o[3] = f2bf(a.w);
  o[4] = f2bf(b.x); o[5] = f2bf(b.y); o[6] = f2bf(b.z); o[7] = f2bf(b.w);
  return o;
}

// ---------------- fused f32 -> bf16 convert: x, Wq, Wk, Wv, Wo ----------------
__global__ __launch_bounds__(256) void cvt5_bf16(
    const float* __restrict__ s0, const float* __restrict__ s1,
    const float* __restrict__ s2, const float* __restrict__ s3,
    const float* __restrict__ s4, short* __restrict__ dst) {
  const int seg = blockIdx.x >> 10;
  const int i = (blockIdx.x & 1023) * 256 + threadIdx.x;
  const float* src = seg == 0 ? s0 : seg == 1 ? s1 : seg == 2 ? s2 : seg == 3 ? s3 : s4;
  f32x4 v = *(const f32x4*)(src + (size_t)i * 4);
  short4v o;
  o.x = f2bf(v.x); o.y = f2bf(v.y); o.z = f2bf(v.z); o.w = f2bf(v.w);
  *(short4v*)(dst + (size_t)seg * (1u << 20) + (size_t)i * 4) = o;
}

// ---------------- GEMM: C[r,n] = sum_m A[r,m] * W[n,m] (+bias) ----------------
// Register-prefetch double buffer: loads for kt+1 issue before compute of kt.
template<int MODE>
__global__ __launch_bounds__(256) void gemm64(
    const short* __restrict__ A, const short* __restrict__ Wbase,
    void* __restrict__ Out, const float* __restrict__ bias0,
    const float* __restrict__ bias1, const float* __restrict__ bias2,
    const int* __restrict__ new_len)
{
  constexpr int LDT = 40;
  __shared__ short As[64 * LDT];
  __shared__ short Bs[64 * LDT];
  const int n0 = blockIdx.x * 64, m0 = blockIdx.y * 64, z = blockIdx.z;
  const short* Wp = Wbase + (size_t)z * (DMODEL * DMODEL);
  const float* bias = (MODE == 0) ? (z == 0 ? bias0 : (z == 1 ? bias1 : bias2)) : bias0;
  const int tid = threadIdx.x, lane = tid & 63, w = tid >> 6;
  const int wm = (w >> 1) * 32, wn = (w & 1) * 32;
  const int lr = lane & 15, lk = lane >> 4;

  const int srow = tid >> 2, soff = (tid & 3) * 8;
  const short* Ag = A  + (size_t)(m0 + srow) * DMODEL + soff;
  const short* Bg = Wp + (size_t)(n0 + srow) * DMODEL + soff;
  short* Al = As + srow * LDT + soff;
  short* Bl = Bs + srow * LDT + soff;

  short8 va = *(const short8*)(Ag);
  short8 vb = *(const short8*)(Bg);
  f32x4 acc[2][2] = {};
  for (int kt = 0; kt < DMODEL / 32; ++kt) {
    __syncthreads();               // previous compute done with LDS
    *(short8*)Al = va;
    *(short8*)Bl = vb;
    if (kt < DMODEL / 32 - 1) {    // prefetch next K-slab (overlaps MFMA below)
      va = *(const short8*)(Ag + (kt + 1) * 32);
      vb = *(const short8*)(Bg + (kt + 1) * 32);
    }
    __syncthreads();
    short8 af[2], bfr[2];
    af[0]  = *(const short8*)(As + (wm + lr) * LDT + lk * 8);
    af[1]  = *(const short8*)(As + (wm + 16 + lr) * LDT + lk * 8);
    bfr[0] = *(const short8*)(Bs + (wn + lr) * LDT + lk * 8);
    bfr[1] = *(const short8*)(Bs + (wn + 16 + lr) * LDT + lk * 8);
#pragma unroll
    for (int i = 0; i < 2; ++i)
#pragma unroll
      for (int j = 0; j < 2; ++j)
        acc[i][j] = __builtin_amdgcn_mfma_f32_16x16x32_bf16(af[i], bfr[j], acc[i][j], 0, 0, 0);
  }
#pragma unroll
  for (int i = 0; i < 2; ++i) {
#pragma unroll
    for (int j = 0; j < 2; ++j) {
      const int col = n0 + wn + j * 16 + lr;
      const float bcol = bias[col];
#pragma unroll
      for (int r = 0; r < 4; ++r) {
        const int row = m0 + wm + i * 16 + lk * 4 + r;
        float v = acc[i][j][r] + bcol;
        if (MODE == 0) {
          ((short*)Out)[(size_t)z * (NB * TNEW * DMODEL) + (size_t)row * DMODEL + col] = f2bf(v);
        } else {
          const int bb = row >> 7, t = row & 127;
          ((float*)Out)[(size_t)row * DMODEL + col] = (t < new_len[bb]) ? v : 0.0f;
        }
      }
    }
  }
}

// ---------------- RoPE + validity masking on q,k (and v mask) ----------------
__global__ __launch_bounds__(256) void rope_mask(
    short* __restrict__ qb, short* __restrict__ kb, short* __restrict__ vb,
    const float* __restrict__ inv_freq, const int* __restrict__ past_len,
    const int* __restrict__ new_len)
{
  const int idx = blockIdx.x * 256 + threadIdx.x;  // B*T*H*32 = 524288
  const int d = idx & 31;
  const int h = (idx >> 5) & 15;
  const int t = (idx >> 9) & 127;
  const int b = idx >> 16;
  const bool valid = t < new_len[b];
  const float pos = (float)(past_len[b] + t);
  float sn, cs;
  sincosf(pos * inv_freq[d], &sn, &cs);
  const size_t base = (size_t)(b * 128 + t) * DMODEL + h * 64 + d;
  const float q1 = bf2f(qb[base]), q2 = bf2f(qb[base + 32]);
  const float k1 = bf2f(kb[base]), k2 = bf2f(kb[base + 32]);
  qb[base]      = valid ? f2bf(q1 * cs - q2 * sn) : (short)0;
  qb[base + 32] = valid ? f2bf(q2 * cs + q1 * sn) : (short)0;
  kb[base]      = valid ? f2bf(k1 * cs - k2 * sn) : (short)0;
  kb[base + 32] = valid ? f2bf(k2 * cs + k1 * sn) : (short)0;
  if (!valid) { vb[base] = 0; vb[base + 32] = 0; }
}

// ---------------- split-K flash attention: partial (O, m, l) per split ----------------
// grid: (bh=128, split). Strided tiles: split s handles kt = s, s+S, s+2S, ...
// Register prefetch of tile t+S issued before compute of tile t.
__global__ __launch_bounds__(512) void attn_split(
    const float* __restrict__ pk, const float* __restrict__ pv,
    const short* __restrict__ qb, const short* __restrict__ kb,
    const short* __restrict__ vb, float* __restrict__ Opart,
    float* __restrict__ Ml, const int* __restrict__ past_len,
    const int* __restrict__ new_len, int splits)
{
  constexpr int LDT = 72;
  __shared__ short Kl[64 * LDT];    // [key][d]
  __shared__ short Vt[64 * LDT];    // [d][key^) swizzled: key' = key ^ (d&56)
  __shared__ short Pl[128 * LDT];   // [q][key], per-wave private rows
  const int bh = blockIdx.x, b = bh >> 4, h = bh & 15;
  const int s = blockIdx.y;
  const int past = past_len[b];
  const int total = past + new_len[b];
  const int tid = threadIdx.x, lane = tid & 63, w = tid >> 6;
  const int lr = lane & 15, lk = lane >> 4;

  const int nt = (total + 63) >> 6;

  float* mlp = Ml + (size_t)(bh * splits + s) * 256;
  float* op  = Opart + (size_t)(bh * splits + s) * (128 * 64);

  if (s >= nt) {  // empty split: weight exp(-3e38-m*)==0 in combine
#pragma unroll
    for (int r = 0; r < 4; ++r) {
      const int q = w * 16 + lk * 4 + r;
      if (lr == 0) { mlp[q] = -3.0e38f; mlp[128 + q] = 0.f; }
    }
    return;
  }

  short8 qf0, qf1;
  {
    const short* qrow = qb + (size_t)(b * 128 + w * 16 + lr) * DMODEL + h * 64;
    qf0 = *(const short8*)(qrow + lk * 8);
    qf1 = *(const short8*)(qrow + 32 + lk * 8);
  }
  float m_run[4], l_run[4];
  f32x4 acc[4] = {};
#pragma unroll
  for (int r = 0; r < 4; ++r) { m_run[r] = -3.0e38f; l_run[r] = 0.f; }

  const int jr = tid >> 3, seg = tid & 7;   // staging: row jr, 8 d's per thread

  // staging registers (prefetch)
  f32x4 kA = {}, kB = {}, vA = {}, vB = {};
  short8 kN = {}, vN = {};
  int smode = 2;
  auto stage_issue = [&](int t) {
    const int j = t * 64 + jr;
    if (j < past) {
      smode = 0;
      const float* kp = pk + ((size_t)(b * 16 + h) * CMAX + j) * 64 + seg * 8;
      const float* vp = pv + ((size_t)(b * 16 + h) * CMAX + j) * 64 + seg * 8;
      kA = *(const f32x4*)kp; kB = *(const f32x4*)(kp + 4);
      vA = *(const f32x4*)vp; vB = *(const f32x4*)(vp + 4);
    } else if (j < total) {
      smode = 1;
      const short* kp = kb + (size_t)(b * 128 + (j - past)) * DMODEL + h * 64 + seg * 8;
      const short* vp = vb + (size_t)(b * 128 + (j - past)) * DMODEL + h * 64 + seg * 8;
      kN = *(const short8*)kp;
      vN = *(const short8*)vp;
    } else {
      smode = 2;
    }
  };

  stage_issue(s);
  for (int kt = s; kt < nt; kt += splits) {
    __syncthreads();   // previous compute done reading Kl/Vt
    {
      short8 kr = {}, vr = {};
      if (smode == 0) { kr = cvt8(kA, kB); vr = cvt8(vA, vB); }
      else if (smode == 1) { kr = kN; vr = vN; }
      *(short8*)(Kl + jr * LDT + seg * 8) = kr;
      // swizzled transpose write: key' = jr ^ (d&56), d = seg*8+i -> d&56 = seg*8
#pragma unroll
      for (int i = 0; i < 8; ++i) Vt[(seg * 8 + i) * LDT + (jr ^ (seg * 8))] = vr[i];
    }
    if (kt + splits < nt) stage_issue(kt + splits);  // prefetch next tile (overlaps compute)
    __syncthreads();

    // ---- S = Q K^T (per wave: 16 q x 64 keys) ----
    f32x4 sc[4];
    __builtin_amdgcn_s_setprio(1);
#pragma unroll
    for (int nf = 0; nf < 4; ++nf) {
      short8 k0 = *(const short8*)(Kl + (nf * 16 + lr) * LDT + lk * 8);
      short8 k1 = *(const short8*)(Kl + (nf * 16 + lr) * LDT + 32 + lk * 8);
      f32x4 zv = {};
      zv = __builtin_amdgcn_mfma_f32_16x16x32_bf16(qf0, k0, zv, 0, 0, 0);
      sc[nf] = __builtin_amdgcn_mfma_f32_16x16x32_bf16(qf1, k1, zv, 0, 0, 0);
    }
    __builtin_amdgcn_s_setprio(0);
    // ---- scale + mask + online softmax ----
    const int kg0 = kt * 64;
    float pmax[4] = {-3.0e38f, -3.0e38f, -3.0e38f, -3.0e38f};
#pragma unroll
    for (int nf = 0; nf < 4; ++nf) {
      const bool ok = (kg0 + nf * 16 + lr) < total;
#pragma unroll
      for (int r = 0; r < 4; ++r) {
        const float sv = ok ? sc[nf][r] * 0.125f : -3.0e38f;
        sc[nf][r] = sv;
        pmax[r] = fmaxf(pmax[r], sv);
      }
    }
#pragma unroll
    for (int r = 0; r < 4; ++r) {
#pragma unroll
      for (int off = 1; off < 16; off <<= 1)
        pmax[r] = fmaxf(pmax[r], __shfl_xor(pmax[r], off));
    }
    float alpha[4], rsum[4];
#pragma unroll
    for (int r = 0; r < 4; ++r) {
      const float mn = fmaxf(m_run[r], pmax[r]);
      alpha[r] = __expf(m_run[r] - mn);
      m_run[r] = mn;
      rsum[r] = 0.f;
    }
#pragma unroll
    for (int nf = 0; nf < 4; ++nf)
#pragma unroll
      for (int r = 0; r < 4; ++r) {
        const float p = __expf(sc[nf][r] - m_run[r]);
        sc[nf][r] = p;
        rsum[r] += p;
      }
#pragma unroll
    for (int r = 0; r < 4; ++r) {
#pragma unroll
      for (int off = 1; off < 16; off <<= 1)
        rsum[r] += __shfl_xor(rsum[r], off);
      l_run[r] = l_run[r] * alpha[r] + rsum[r];
    }
#pragma unroll
    for (int nf = 0; nf < 4; ++nf)
#pragma unroll
      for (int r = 0; r < 4; ++r) acc[nf][r] *= alpha[r];

    // ---- P -> LDS (C-layout rows), then PV MFMAs (same-wave RAW: in-order DS) ----
#pragma unroll
    for (int nf = 0; nf < 4; ++nf)
#pragma unroll
      for (int r = 0; r < 4; ++r)
        Pl[(w * 16 + lk * 4 + r) * LDT + nf * 16 + lr] = f2bf(sc[nf][r]);
    __builtin_amdgcn_s_setprio(1);
#pragma unroll
    for (int kf = 0; kf < 2; ++kf) {
      short8 pf = *(const short8*)(Pl + (w * 16 + lr) * LDT + kf * 32 + lk * 8);
#pragma unroll
      for (int nf = 0; nf < 4; ++nf) {
        const int dd = nf * 16 + lr;
        short8 vf = *(const short8*)(Vt + dd * LDT + ((kf * 32 + lk * 8) ^ (dd & 56)));
        acc[nf] = __builtin_amdgcn_mfma_f32_16x16x32_bf16(pf, vf, acc[nf], 0, 0, 0);
      }
    }
    __builtin_amdgcn_s_setprio(0);
  }
  // ---- epilogue: partial O (unnormalized), m, l ----
#pragma unroll
  for (int nf = 0; nf < 4; ++nf)
#pragma unroll
    for (int r = 0; r < 4; ++r) {
      const int q = w * 16 + lk * 4 + r, d = nf * 16 + lr;
      op[(size_t)q * 64 + d] = acc[nf][r];
    }
#pragma unroll
  for (int r = 0; r < 4; ++r) {
    const int q = w * 16 + lk * 4 + r;
    if (lr == 0) { mlp[q] = m_run[r]; mlp[128 + q] = l_run[r]; }
  }
}

// ---------------- combine partials -> ctx (bf16) ----------------
__global__ __launch_bounds__(256) void attn_combine(
    const float* __restrict__ Opart, const float* __restrict__ Ml,
    short* __restrict__ ctxb, int splits)
{
  const int bh = blockIdx.x, b = bh >> 4, h = bh & 15;
  const int q = blockIdx.y * 16 + (threadIdx.x >> 4);
  const int dv = (threadIdx.x & 15) * 4;
  const float* mlb = Ml + (size_t)bh * splits * 256;
  float mstar = -3.0e38f;
  for (int s = 0; s < splits; ++s)
    mstar = fmaxf(mstar, mlb[s * 256 + q]);
  float lsum = 0.f;
  f32x4 o = {};
  for (int s = 0; s < splits; ++s) {
    const float ws = __expf(mlb[s * 256 + q] - mstar);
    lsum += ws * mlb[s * 256 + 128 + q];
    f32x4 ov = *(const f32x4*)(Opart + ((size_t)(bh * splits + s) * 128 + q) * 64 + dv);
    o.x += ws * ov.x; o.y += ws * ov.y; o.z += ws * ov.z; o.w += ws * ov.w;
  }
  const float inv = 1.0f / lsum;
  short4v r;
  r.x = f2bf(o.x * inv); r.y = f2bf(o.y * inv); r.z = f2bf(o.z * inv); r.w = f2bf(o.w * inv);
  *(short4v*)(ctxb + (size_t)(b * 128 + q) * DMODEL + h * 64 + dv) = r;
}

// ---------------- launcher ----------------
extern "C" void kernel_launch(void* const* d_in, const int* in_sizes, int n_in,
                              void* d_out, int out_size, void* d_ws, size_t ws_size,
                              hipStream_t stream) {
  const float* x      = (const float*)d_in[0];
  const float* past_k = (const float*)d_in[1];
  const float* past_v = (const float*)d_in[2];
  const float* Wq = (const float*)d_in[3];
  const float* bq = (const float*)d_in[4];
  const float* Wk = (const float*)d_in[5];
  const float* bk = (const float*)d_in[6];
  const float* Wv = (const float*)d_in[7];
  const float* bv = (const float*)d_in[8];
  const float* Wo = (const float*)d_in[9];
  const float* bo = (const float*)d_in[10];
  const float* inv_freq = (const float*)d_in[11];
  const int* past_len = (const int*)d_in[12];
  const int* new_len  = (const int*)d_in[13];

  short* wsb = (short*)d_ws;
  const size_t M1 = 1u << 20;
  short* Xb  = wsb;
  short* Wqb = wsb + 1 * M1;
  short* Wob = wsb + 4 * M1;
  short* qb  = wsb + 5 * M1;
  short* kb  = wsb + 6 * M1;
  short* vb  = wsb + 7 * M1;
  short* ctx = wsb + 8 * M1;
  float* Opart = (float*)(wsb + 9 * M1);

  int splits = 1;
  for (int s = 8; s >= 1; s >>= 1) {
    size_t need = 9 * M1 * sizeof(short) +
                  (size_t)s * 128 * (128 * 64 + 256) * sizeof(float);
    if (need <= ws_size) { splits = s; break; }
  }
  float* Ml = Opart + (size_t)128 * splits * (128 * 64);

  cvt5_bf16<<<5120, 256, 0, stream>>>(x, Wq, Wk, Wv, Wo, wsb);

  gemm64<0><<<dim3(16, 16, 3), 256, 0, stream>>>(Xb, Wqb, (void*)qb, bq, bk, bv, nullptr);
  rope_mask<<<2048, 256, 0, stream>>>(qb, kb, vb, inv_freq, past_len, new_len);
  attn_split<<<dim3(128, splits), 512, 0, stream>>>(past_k, past_v, qb, kb, vb,
                                                    Opart, Ml, past_len, new_len, splits);
  attn_combine<<<dim3(128, 8), 256, 0, stream>>>(Opart, Ml, ctx, splits);
  gemm64<1><<<dim3(16, 16, 1), 256, 0, stream>>>(ctx, Wob, d_out, bo, nullptr, nullptr, new_len);
}